// Round 1
// baseline (288.587 us; speedup 1.0000x reference)
//
#include <hip/hip_runtime.h>
#include <hip/hip_bf16.h>

typedef __bf16 bf16x8 __attribute__((ext_vector_type(8)));
typedef __bf16 bf16x4 __attribute__((ext_vector_type(4)));
typedef float  f32x4  __attribute__((ext_vector_type(4)));

// Problem constants: B=32, N=4096, H=256, TDIM=128, K=2, R=2

// ---- workspace byte offsets (total ~6.7 MB) ----
static constexpr size_t WS_A     = 0;                   // 5 f32 combine coeffs
static constexpr size_t WS_TOUT  = 1024;                // t_out [32,256] f32
static constexpr size_t WS_Z1    = 65536;               // z1..z4 [32,4096] f32 each
static constexpr size_t WS_ZSTR  = 524288;
static constexpr size_t WS_H0    = WS_Z1 + 4 * WS_ZSTR; // h0 [32,256] f32 (atomic acc)
static constexpr size_t WS_G2F   = WS_H0 + 32768;       // g2 [32,4096] f32
static constexpr size_t WS_UB    = WS_G2F + 524288;     // u [32,256] bf16
static constexpr size_t WS_WMAPT = 2752512;             // w_map^T [256,4096] bf16
static constexpr size_t WS_WO2T  = WS_WMAPT + 2097152;  // w_o2^T [4096,256] bf16

__device__ __forceinline__ f32x4 mfma16(bf16x8 a, bf16x8 b, f32x4 c) {
    return __builtin_amdgcn_mfma_f32_16x16x32_bf16(a, b, c, 0, 0, 0);
}

__device__ __forceinline__ bf16x8 cvt8(const float* p) {
    f32x4 lo = *(const f32x4*)p;
    f32x4 hi = *(const f32x4*)(p + 4);
    bf16x8 r;
    r[0] = (__bf16)lo[0]; r[1] = (__bf16)lo[1]; r[2] = (__bf16)lo[2]; r[3] = (__bf16)lo[3];
    r[4] = (__bf16)hi[0]; r[5] = (__bf16)hi[1]; r[6] = (__bf16)hi[2]; r[7] = (__bf16)hi[3];
    return r;
}

__device__ __forceinline__ float silu_f(float x) { return x / (1.0f + __expf(-x)); }

// 32x32 tile transpose f32 -> bf16 via LDS
__device__ __forceinline__ void transpose_tile(const float* __restrict__ src, int sstride,
                                               __bf16* __restrict__ dst, int dstride,
                                               int r0, int c0, float* sh, int tid) {
    const int r = tid >> 3, cg = (tid & 7) * 4;
    f32x4 v = *(const f32x4*)(src + (size_t)(r0 + r) * sstride + c0 + cg);
    sh[r * 33 + cg + 0] = v[0];
    sh[r * 33 + cg + 1] = v[1];
    sh[r * 33 + cg + 2] = v[2];
    sh[r * 33 + cg + 3] = v[3];
    __syncthreads();
    bf16x4 o;
    o[0] = (__bf16)sh[(cg + 0) * 33 + r];
    o[1] = (__bf16)sh[(cg + 1) * 33 + r];
    o[2] = (__bf16)sh[(cg + 2) * 33 + r];
    o[3] = (__bf16)sh[(cg + 3) * 33 + r];
    *(bf16x4*)(dst + (size_t)(c0 + r) * dstride + r0 + cg) = o;
}

// Node 1: coefficients, time-MLP, zero z1..z4+h0, weight transposes.
__global__ __launch_bounds__(256) void prep_kernel(
    const float* __restrict__ t,
    const float* __restrict__ w_g1, const float* __restrict__ w_g2,
    const float* __restrict__ w_t1, const float* __restrict__ b_t1,
    const float* __restrict__ w_t2, const float* __restrict__ b_t2,
    const float* __restrict__ w_map, const float* __restrict__ w_o2,
    char* __restrict__ ws)
{
    __shared__ float sh[1056];
    const int bi = blockIdx.x, tid = threadIdx.x;
    if (bi == 0) {
        // a_p = sum_{k1+k2=p} sum_h w_g1[0,h,k1]*w_g2[h,0,k2]
        if (tid < 9) {
            const int k1 = tid / 3, k2 = tid % 3;
            float s = 0.f;
            for (int h = 0; h < 256; ++h) s += w_g1[h * 3 + k1] * w_g2[h * 3 + k2];
            sh[tid] = s;
        }
        __syncthreads();
        if (tid == 0) {
            float* a = (float*)(ws + WS_A);
            a[0] = sh[0];
            a[1] = sh[1] + sh[3];
            a[2] = sh[2] + sh[4] + sh[6];
            a[3] = sh[5] + sh[7];
            a[4] = sh[8];
        }
    } else if (bi < 33) {
        // time embedding -> 2-layer MLP -> t_out [b,256]
        const int b = bi - 1;
        float* t_out = (float*)(ws + WS_TOUT);
        if (tid < 64) {
            float fr = __expf(-9.210340371976184f * (float)tid * (1.0f / 64.0f));
            float ang = t[b] * fr;
            sh[tid]      = __cosf(ang);
            sh[64 + tid] = __sinf(ang);
        }
        __syncthreads();
        float acc = b_t1[tid];
        for (int j = 0; j < 128; ++j) acc += sh[j] * w_t1[j * 256 + tid];
        sh[128 + tid] = silu_f(acc);
        __syncthreads();
        float acc2 = b_t2[tid];
        for (int j = 0; j < 256; ++j) acc2 += sh[128 + j] * w_t2[j * 256 + tid];
        t_out[b * 256 + tid] = acc2;
    } else if (bi < 553) {
        // zero z1..z4 and h0 (contiguous region, 520 * 4KB)
        f32x4* p = (f32x4*)(ws + WS_Z1 + (size_t)(bi - 33) * 4096);
        f32x4 z = {0.f, 0.f, 0.f, 0.f};
        p[tid] = z;
    } else if (bi < 1577) {
        // w_map [4096,256] f32 -> w_mapT [256,4096] bf16
        const int ti = bi - 553;
        transpose_tile(w_map, 256, (__bf16*)(ws + WS_WMAPT), 4096,
                       (ti >> 3) * 32, (ti & 7) * 32, sh, tid);
    } else {
        // w_o2 [256,4096] f32 -> w_o2T [4096,256] bf16
        const int ti = bi - 1577;
        transpose_tile(w_o2, 4096, (__bf16*)(ws + WS_WO2T), 256,
                       (ti & 7) * 32, (ti >> 3) * 32, sh, tid);
    }
}

// Nodes 2-5: zout[b,m] += sum_n L[m,n] * zin[b,n].  z layout [32, 4096].
// Grid 512: (msuper 0..127) x (kchunk 0..3); 4 waves split the 1024 kchunk.
__global__ __launch_bounds__(256) void hop_kernel(
    const float* __restrict__ L, const float* __restrict__ zin,
    float* __restrict__ zout)
{
    __shared__ float red[4][32][32];
    const int bi = blockIdx.x, tid = threadIdx.x;
    const int wave = tid >> 6, lane = tid & 63;
    const int l15 = lane & 15, q = lane >> 4;
    const int m0 = (bi >> 2) * 32;
    const int kbase = (bi & 3) * 1024 + wave * 256;

    const float* a0p = L + (size_t)(m0 + l15) * 4096;
    const float* a1p = a0p + (size_t)16 * 4096;
    const float* b0p = zin + (size_t)l15 * 4096;
    const float* b1p = zin + (size_t)(l15 + 16) * 4096;

    f32x4 acc00 = {0,0,0,0}, acc01 = {0,0,0,0}, acc10 = {0,0,0,0}, acc11 = {0,0,0,0};
#pragma unroll
    for (int ks = 0; ks < 8; ++ks) {
        const int k = kbase + ks * 32 + q * 8;
        bf16x8 a0 = cvt8(a0p + k);
        bf16x8 a1 = cvt8(a1p + k);
        bf16x8 b0 = cvt8(b0p + k);
        bf16x8 b1 = cvt8(b1p + k);
        acc00 = mfma16(a0, b0, acc00);
        acc01 = mfma16(a0, b1, acc01);
        acc10 = mfma16(a1, b0, acc10);
        acc11 = mfma16(a1, b1, acc11);
    }
    // C/D layout: col = lane&15 (b-dim), row = q*4+reg (m-dim)  [m89-verified]
#pragma unroll
    for (int r = 0; r < 4; ++r) {
        red[wave][q * 4 + r][l15]           = acc00[r];
        red[wave][q * 4 + r][l15 + 16]      = acc01[r];
        red[wave][16 + q * 4 + r][l15]      = acc10[r];
        red[wave][16 + q * 4 + r][l15 + 16] = acc11[r];
    }
    __syncthreads();
    const int b_l = tid >> 3, mb = (tid & 7) * 4;
#pragma unroll
    for (int j = 0; j < 4; ++j) {
        const int m = mb + j;
        float v = red[0][m][b_l] + red[1][m][b_l] + red[2][m][b_l] + red[3][m][b_l];
        atomicAdd(zout + (size_t)b_l * 4096 + m0 + m, v);
    }
}

// Node 6: g2 = a0*x + a1*z1 + a2*z2 + a3*z3 + a4*z4
__global__ __launch_bounds__(256) void combine_kernel(
    const float* __restrict__ x,
    const float* __restrict__ z1, const float* __restrict__ z2,
    const float* __restrict__ z3, const float* __restrict__ z4,
    const float* __restrict__ a, float* __restrict__ g2)
{
    const int i = blockIdx.x * 256 + threadIdx.x;
    const float a0 = a[0], a1 = a[1], a2 = a[2], a3 = a[3], a4 = a[4];
    f32x4 r = a0 * ((const f32x4*)x)[i] + a1 * ((const f32x4*)z1)[i]
            + a2 * ((const f32x4*)z2)[i] + a3 * ((const f32x4*)z3)[i]
            + a4 * ((const f32x4*)z4)[i];
    ((f32x4*)g2)[i] = r;
}

// Node 7: h0[b,h] += sum_n g2[b,n] * w_map[n,h]   (K split x2, 4 waves split 2048)
__global__ __launch_bounds__(256) void map_gemm_kernel(
    const float* __restrict__ g2, const __bf16* __restrict__ w_mapT,
    float* __restrict__ h0)
{
    __shared__ float red[4][16][32];
    const int bi = blockIdx.x, tid = threadIdx.x;
    const int wave = tid >> 6, lane = tid & 63;
    const int l15 = lane & 15, q = lane >> 4;
    const int btile = bi & 1;
    const int hp = (bi >> 1) & 7;
    const int kc = bi >> 4;
    const int kbase = kc * 2048 + wave * 512;

    const float*  ap  = g2 + (size_t)(btile * 16 + l15) * 4096;
    const __bf16* bp0 = w_mapT + (size_t)(hp * 32 + l15) * 4096;
    const __bf16* bp1 = w_mapT + (size_t)(hp * 32 + 16 + l15) * 4096;

    f32x4 acc0 = {0,0,0,0}, acc1 = {0,0,0,0};
#pragma unroll
    for (int ks = 0; ks < 16; ++ks) {
        const int k = kbase + ks * 32 + q * 8;
        bf16x8 a  = cvt8(ap + k);
        bf16x8 b0 = *(const bf16x8*)(bp0 + k);
        bf16x8 b1 = *(const bf16x8*)(bp1 + k);
        acc0 = mfma16(a, b0, acc0);
        acc1 = mfma16(a, b1, acc1);
    }
#pragma unroll
    for (int r = 0; r < 4; ++r) {
        red[wave][q * 4 + r][l15]      = acc0[r];
        red[wave][q * 4 + r][l15 + 16] = acc1[r];
    }
    __syncthreads();
    const int b_l = tid >> 4, hl = tid & 15;
#pragma unroll
    for (int s = 0; s < 2; ++s) {
        const int h_l = hl + s * 16;
        float v = red[0][b_l][h_l] + red[1][b_l][h_l] + red[2][b_l][h_l] + red[3][b_l][h_l];
        atomicAdd(h0 + (size_t)(btile * 16 + b_l) * 256 + hp * 32 + h_l, v);
    }
}

// Node 8: h = h0 + b_map; 2x(3-layer silu MLP + residual)/sqrt2; u = silu((h+t_out)@w_o1+b_o1)
__global__ __launch_bounds__(256) void resnet_kernel(
    const float* __restrict__ h0, const float* __restrict__ b_map,
    const float* __restrict__ res_w, const float* __restrict__ res_b,
    const float* __restrict__ t_out, const float* __restrict__ w_o1,
    const float* __restrict__ b_o1, __bf16* __restrict__ u_b)
{
    __shared__ float zs[256];
    const int b = blockIdx.x, tid = threadIdx.x;
    float hv = h0[b * 256 + tid] + b_map[tid];
#pragma unroll
    for (int r = 0; r < 2; ++r) {
        float z = hv;
        for (int i = 0; i < 3; ++i) {
            zs[tid] = z;
            __syncthreads();
            const float* W = res_w + ((size_t)(r * 3 + i) << 16) + tid;
            float a0 = 0, a1 = 0, a2 = 0, a3 = 0;
            for (int j = 0; j < 256; j += 4) {
                a0 += zs[j]     * W[(j)     * 256];
                a1 += zs[j + 1] * W[(j + 1) * 256];
                a2 += zs[j + 2] * W[(j + 2) * 256];
                a3 += zs[j + 3] * W[(j + 3) * 256];
            }
            z = silu_f(res_b[(r * 3 + i) * 256 + tid] + ((a0 + a1) + (a2 + a3)));
            __syncthreads();
        }
        hv = (hv + z) * 0.70710678118654752f;
    }
    const float v = hv + t_out[b * 256 + tid];
    zs[tid] = v;
    __syncthreads();
    float a0 = 0, a1 = 0, a2 = 0, a3 = 0;
    for (int j = 0; j < 256; j += 4) {
        a0 += zs[j]     * w_o1[(j)     * 256 + tid];
        a1 += zs[j + 1] * w_o1[(j + 1) * 256 + tid];
        a2 += zs[j + 2] * w_o1[(j + 2) * 256 + tid];
        a3 += zs[j + 3] * w_o1[(j + 3) * 256 + tid];
    }
    u_b[b * 256 + tid] = (__bf16)silu_f(b_o1[tid] + ((a0 + a1) + (a2 + a3)));
}

// Node 9: out[b,n] = sum_h u[b,h] * w_o2[h,n] + b_o2[n]   (K=256, full-K per wave)
__global__ __launch_bounds__(256) void out_gemm_kernel(
    const __bf16* __restrict__ u_b, const __bf16* __restrict__ w_o2T,
    const float* __restrict__ b_o2, float* __restrict__ out)
{
    const int tid = threadIdx.x;
    const int wave = tid >> 6, lane = tid & 63;
    const int l15 = lane & 15, q = lane >> 4;
    const int g = blockIdx.x * 4 + wave;
    const int btile = g & 1;
    const int n0 = (g >> 1) * 32;

    const __bf16* ap  = u_b + (size_t)(btile * 16 + l15) * 256;
    const __bf16* bp0 = w_o2T + (size_t)(n0 + l15) * 256;
    const __bf16* bp1 = w_o2T + (size_t)(n0 + 16 + l15) * 256;

    f32x4 acc0 = {0,0,0,0}, acc1 = {0,0,0,0};
#pragma unroll
    for (int ks = 0; ks < 8; ++ks) {
        const int k = ks * 32 + q * 8;
        bf16x8 a  = *(const bf16x8*)(ap + k);
        bf16x8 b0 = *(const bf16x8*)(bp0 + k);
        bf16x8 b1 = *(const bf16x8*)(bp1 + k);
        acc0 = mfma16(a, b0, acc0);
        acc1 = mfma16(a, b1, acc1);
    }
    const int row = btile * 16 + q * 4;
    const int na = n0 + l15, nb = n0 + 16 + l15;
#pragma unroll
    for (int r = 0; r < 4; ++r) {
        out[(size_t)(row + r) * 4096 + na] = acc0[r] + b_o2[na];
        out[(size_t)(row + r) * 4096 + nb] = acc1[r] + b_o2[nb];
    }
}

extern "C" void kernel_launch(void* const* d_in, const int* in_sizes, int n_in,
                              void* d_out, int out_size, void* d_ws, size_t ws_size,
                              hipStream_t stream)
{
    (void)in_sizes; (void)n_in; (void)out_size; (void)ws_size;
    const float* x     = (const float*)d_in[0];
    const float* t     = (const float*)d_in[1];
    const float* L     = (const float*)d_in[2];
    const float* w_g1  = (const float*)d_in[3];
    const float* w_g2  = (const float*)d_in[4];
    const float* w_t1  = (const float*)d_in[5];
    const float* b_t1  = (const float*)d_in[6];
    const float* w_t2  = (const float*)d_in[7];
    const float* b_t2  = (const float*)d_in[8];
    const float* w_map = (const float*)d_in[9];
    const float* b_map = (const float*)d_in[10];
    const float* res_w = (const float*)d_in[11];
    const float* res_b = (const float*)d_in[12];
    const float* w_o1  = (const float*)d_in[13];
    const float* b_o1  = (const float*)d_in[14];
    const float* w_o2  = (const float*)d_in[15];
    const float* b_o2  = (const float*)d_in[16];
    float* out = (float*)d_out;
    char* ws = (char*)d_ws;

    float* a_c  = (float*)(ws + WS_A);
    float* tout = (float*)(ws + WS_TOUT);
    float* z1   = (float*)(ws + WS_Z1);
    float* z2   = (float*)(ws + WS_Z1 + WS_ZSTR);
    float* z3   = (float*)(ws + WS_Z1 + 2 * WS_ZSTR);
    float* z4   = (float*)(ws + WS_Z1 + 3 * WS_ZSTR);
    float* h0   = (float*)(ws + WS_H0);
    float* g2   = (float*)(ws + WS_G2F);
    __bf16* u_b    = (__bf16*)(ws + WS_UB);
    __bf16* w_mapT = (__bf16*)(ws + WS_WMAPT);
    __bf16* w_o2T  = (__bf16*)(ws + WS_WO2T);

    prep_kernel<<<2601, 256, 0, stream>>>(t, w_g1, w_g2, w_t1, b_t1, w_t2, b_t2,
                                          w_map, w_o2, ws);
    hop_kernel<<<512, 256, 0, stream>>>(L, x,  z1);
    hop_kernel<<<512, 256, 0, stream>>>(L, z1, z2);
    hop_kernel<<<512, 256, 0, stream>>>(L, z2, z3);
    hop_kernel<<<512, 256, 0, stream>>>(L, z3, z4);
    combine_kernel<<<128, 256, 0, stream>>>(x, z1, z2, z3, z4, a_c, g2);
    map_gemm_kernel<<<32, 256, 0, stream>>>(g2, w_mapT, h0);
    resnet_kernel<<<32, 256, 0, stream>>>(h0, b_map, res_w, res_b, tout, w_o1, b_o1, u_b);
    out_gemm_kernel<<<64, 256, 0, stream>>>(u_b, w_o2T, b_o2, out);
}

// Round 2
// 236.580 us; speedup vs baseline: 1.2198x; 1.2198x over previous
//
#include <hip/hip_runtime.h>
#include <hip/hip_bf16.h>

typedef __bf16 bf16x8 __attribute__((ext_vector_type(8)));
typedef __bf16 bf16x4 __attribute__((ext_vector_type(4)));
typedef float  f32x4  __attribute__((ext_vector_type(4)));

// Problem constants: B=32, N=4096, H=256, TDIM=128, K=2, R=2

// ---- workspace byte offsets (total ~6.7 MB) ----
static constexpr size_t WS_A     = 0;                   // 5 f32 combine coeffs
static constexpr size_t WS_TOUT  = 1024;                // t_out [32,256] f32
static constexpr size_t WS_Z1    = 65536;               // z1..z4 [32,4096] f32 each
static constexpr size_t WS_ZSTR  = 524288;
static constexpr size_t WS_H0    = WS_Z1 + 4 * WS_ZSTR; // h0 [32,256] f32 (atomic acc)
static constexpr size_t WS_G2F   = WS_H0 + 32768;       // g2 [32,4096] f32
static constexpr size_t WS_UB    = WS_G2F + 524288;     // u [32,256] bf16
static constexpr size_t WS_WMAPT = 2752512;             // w_map^T [256,4096] bf16
static constexpr size_t WS_WO2T  = WS_WMAPT + 2097152;  // w_o2^T [4096,256] bf16

__device__ __forceinline__ f32x4 mfma16(bf16x8 a, bf16x8 b, f32x4 c) {
    return __builtin_amdgcn_mfma_f32_16x16x32_bf16(a, b, c, 0, 0, 0);
}

__device__ __forceinline__ bf16x8 cvt8(const float* p) {
    f32x4 lo = *(const f32x4*)p;
    f32x4 hi = *(const f32x4*)(p + 4);
    bf16x8 r;
    r[0] = (__bf16)lo[0]; r[1] = (__bf16)lo[1]; r[2] = (__bf16)lo[2]; r[3] = (__bf16)lo[3];
    r[4] = (__bf16)hi[0]; r[5] = (__bf16)hi[1]; r[6] = (__bf16)hi[2]; r[7] = (__bf16)hi[3];
    return r;
}

__device__ __forceinline__ float silu_f(float x) { return x / (1.0f + __expf(-x)); }

// 32x32 tile transpose f32 -> bf16 via LDS
__device__ __forceinline__ void transpose_tile(const float* __restrict__ src, int sstride,
                                               __bf16* __restrict__ dst, int dstride,
                                               int r0, int c0, float* sh, int tid) {
    const int r = tid >> 3, cg = (tid & 7) * 4;
    f32x4 v = *(const f32x4*)(src + (size_t)(r0 + r) * sstride + c0 + cg);
    sh[r * 33 + cg + 0] = v[0];
    sh[r * 33 + cg + 1] = v[1];
    sh[r * 33 + cg + 2] = v[2];
    sh[r * 33 + cg + 3] = v[3];
    __syncthreads();
    bf16x4 o;
    o[0] = (__bf16)sh[(cg + 0) * 33 + r];
    o[1] = (__bf16)sh[(cg + 1) * 33 + r];
    o[2] = (__bf16)sh[(cg + 2) * 33 + r];
    o[3] = (__bf16)sh[(cg + 3) * 33 + r];
    *(bf16x4*)(dst + (size_t)(c0 + r) * dstride + r0 + cg) = o;
}

// Node 1: coefficients, time-MLP, zero z1..z4+h0, weight transposes.
__global__ __launch_bounds__(256) void prep_kernel(
    const float* __restrict__ t,
    const float* __restrict__ w_g1, const float* __restrict__ w_g2,
    const float* __restrict__ w_t1, const float* __restrict__ b_t1,
    const float* __restrict__ w_t2, const float* __restrict__ b_t2,
    const float* __restrict__ w_map, const float* __restrict__ w_o2,
    char* __restrict__ ws)
{
    __shared__ float sh[1056];
    const int bi = blockIdx.x, tid = threadIdx.x;
    if (bi == 0) {
        if (tid < 9) {
            const int k1 = tid / 3, k2 = tid % 3;
            float s = 0.f;
            for (int h = 0; h < 256; ++h) s += w_g1[h * 3 + k1] * w_g2[h * 3 + k2];
            sh[tid] = s;
        }
        __syncthreads();
        if (tid == 0) {
            float* a = (float*)(ws + WS_A);
            a[0] = sh[0];
            a[1] = sh[1] + sh[3];
            a[2] = sh[2] + sh[4] + sh[6];
            a[3] = sh[5] + sh[7];
            a[4] = sh[8];
        }
    } else if (bi < 33) {
        const int b = bi - 1;
        float* t_out = (float*)(ws + WS_TOUT);
        if (tid < 64) {
            float fr = __expf(-9.210340371976184f * (float)tid * (1.0f / 64.0f));
            float ang = t[b] * fr;
            sh[tid]      = __cosf(ang);
            sh[64 + tid] = __sinf(ang);
        }
        __syncthreads();
        float acc = b_t1[tid];
        for (int j = 0; j < 128; ++j) acc += sh[j] * w_t1[j * 256 + tid];
        sh[128 + tid] = silu_f(acc);
        __syncthreads();
        float acc2 = b_t2[tid];
        for (int j = 0; j < 256; ++j) acc2 += sh[128 + j] * w_t2[j * 256 + tid];
        t_out[b * 256 + tid] = acc2;
    } else if (bi < 553) {
        f32x4* p = (f32x4*)(ws + WS_Z1 + (size_t)(bi - 33) * 4096);
        f32x4 z = {0.f, 0.f, 0.f, 0.f};
        p[tid] = z;
    } else if (bi < 1577) {
        const int ti = bi - 553;
        transpose_tile(w_map, 256, (__bf16*)(ws + WS_WMAPT), 4096,
                       (ti >> 3) * 32, (ti & 7) * 32, sh, tid);
    } else {
        const int ti = bi - 1577;
        transpose_tile(w_o2, 4096, (__bf16*)(ws + WS_WO2T), 256,
                       (ti & 7) * 32, (ti >> 3) * 32, sh, tid);
    }
}

// Nodes 2-5: zout[b,m] += sum_n L[m,n] * zin[b,n].  z layout [32, 4096].
// Grid 512 x 512 threads: (msuper 0..127) x (kchunk 0..3); 8 waves split the 1024 kchunk.
__global__ __launch_bounds__(512) void hop_kernel(
    const float* __restrict__ L, const float* __restrict__ zin,
    float* __restrict__ zout)
{
    __shared__ float red[8][32][33];  // ~34 KB, padded stride 33 vs bank conflicts
    const int bi = blockIdx.x, tid = threadIdx.x;
    const int wave = tid >> 6, lane = tid & 63;
    const int l15 = lane & 15, q = lane >> 4;
    const int m0 = (bi >> 2) * 32;
    const int kbase = (bi & 3) * 1024 + wave * 128;

    const float* a0p = L + (size_t)(m0 + l15) * 4096;
    const float* a1p = a0p + (size_t)16 * 4096;
    const float* b0p = zin + (size_t)l15 * 4096;
    const float* b1p = zin + (size_t)(l15 + 16) * 4096;

    f32x4 acc00 = {0,0,0,0}, acc01 = {0,0,0,0}, acc10 = {0,0,0,0}, acc11 = {0,0,0,0};
#pragma unroll
    for (int ks = 0; ks < 4; ++ks) {
        const int k = kbase + ks * 32 + q * 8;
        bf16x8 a0 = cvt8(a0p + k);
        bf16x8 a1 = cvt8(a1p + k);
        bf16x8 b0 = cvt8(b0p + k);
        bf16x8 b1 = cvt8(b1p + k);
        acc00 = mfma16(a0, b0, acc00);
        acc01 = mfma16(a0, b1, acc01);
        acc10 = mfma16(a1, b0, acc10);
        acc11 = mfma16(a1, b1, acc11);
    }
    // C/D layout: col = lane&15 (b-dim), row = q*4+reg (m-dim)
#pragma unroll
    for (int r = 0; r < 4; ++r) {
        red[wave][q * 4 + r][l15]           = acc00[r];
        red[wave][q * 4 + r][l15 + 16]      = acc01[r];
        red[wave][16 + q * 4 + r][l15]      = acc10[r];
        red[wave][16 + q * 4 + r][l15 + 16] = acc11[r];
    }
    __syncthreads();
#pragma unroll
    for (int o = tid; o < 1024; o += 512) {
        const int m = o & 31, bcol = o >> 5;
        float v = 0.f;
#pragma unroll
        for (int w = 0; w < 8; ++w) v += red[w][m][bcol];
        atomicAdd(zout + (size_t)bcol * 4096 + m0 + m, v);
    }
}

// Node 6: g2 = a0*x + a1*z1 + a2*z2 + a3*z3 + a4*z4
__global__ __launch_bounds__(256) void combine_kernel(
    const float* __restrict__ x,
    const float* __restrict__ z1, const float* __restrict__ z2,
    const float* __restrict__ z3, const float* __restrict__ z4,
    const float* __restrict__ a, float* __restrict__ g2)
{
    const int i = blockIdx.x * 256 + threadIdx.x;
    const float a0 = a[0], a1 = a[1], a2 = a[2], a3 = a[3], a4 = a[4];
    f32x4 r = a0 * ((const f32x4*)x)[i] + a1 * ((const f32x4*)z1)[i]
            + a2 * ((const f32x4*)z2)[i] + a3 * ((const f32x4*)z3)[i]
            + a4 * ((const f32x4*)z4)[i];
    ((f32x4*)g2)[i] = r;
}

// Node 7: h0[b,h] += sum_n g2[b,n] * w_map[n,h]   (grid 128: btile x hp x 8 kc; 4 waves x 128k)
__global__ __launch_bounds__(256) void map_gemm_kernel(
    const float* __restrict__ g2, const __bf16* __restrict__ w_mapT,
    float* __restrict__ h0)
{
    __shared__ float red[4][16][32];
    const int bi = blockIdx.x, tid = threadIdx.x;
    const int wave = tid >> 6, lane = tid & 63;
    const int l15 = lane & 15, q = lane >> 4;
    const int btile = bi & 1;
    const int hp = (bi >> 1) & 7;
    const int kc = bi >> 4;                 // 0..7
    const int kbase = kc * 512 + wave * 128;

    const float*  ap  = g2 + (size_t)(btile * 16 + l15) * 4096;
    const __bf16* bp0 = w_mapT + (size_t)(hp * 32 + l15) * 4096;
    const __bf16* bp1 = w_mapT + (size_t)(hp * 32 + 16 + l15) * 4096;

    f32x4 acc0 = {0,0,0,0}, acc1 = {0,0,0,0};
#pragma unroll
    for (int ks = 0; ks < 4; ++ks) {
        const int k = kbase + ks * 32 + q * 8;
        bf16x8 a  = cvt8(ap + k);
        bf16x8 b0 = *(const bf16x8*)(bp0 + k);
        bf16x8 b1 = *(const bf16x8*)(bp1 + k);
        acc0 = mfma16(a, b0, acc0);
        acc1 = mfma16(a, b1, acc1);
    }
#pragma unroll
    for (int r = 0; r < 4; ++r) {
        red[wave][q * 4 + r][l15]      = acc0[r];
        red[wave][q * 4 + r][l15 + 16] = acc1[r];
    }
    __syncthreads();
    const int b_l = tid >> 4, hl = tid & 15;
#pragma unroll
    for (int s = 0; s < 2; ++s) {
        const int h_l = hl + s * 16;
        float v = red[0][b_l][h_l] + red[1][b_l][h_l] + red[2][b_l][h_l] + red[3][b_l][h_l];
        atomicAdd(h0 + (size_t)(btile * 16 + b_l) * 256 + hp * 32 + h_l, v);
    }
}

// Node 8: h = h0 + b_map; 2x(3-layer silu MLP + residual)/sqrt2; u = silu((h+t_out)@w_o1+b_o1)
// 1024 threads: col = tid&255, kg = tid>>8 (4-way K-split per layer, LDS reduce).
__global__ __launch_bounds__(1024) void resnet_kernel(
    const float* __restrict__ h0, const float* __restrict__ b_map,
    const float* __restrict__ res_w, const float* __restrict__ res_b,
    const float* __restrict__ t_out, const float* __restrict__ w_o1,
    const float* __restrict__ b_o1, __bf16* __restrict__ u_b)
{
    __shared__ float zs[256];
    __shared__ float part[4][256];
    const int b = blockIdx.x, tid = threadIdx.x;
    const int col = tid & 255, kg = tid >> 8;

    float hv = 0.f;
    if (kg == 0) {
        hv = h0[b * 256 + col] + b_map[col];
        zs[col] = hv;
    }
    __syncthreads();

#pragma unroll
    for (int r = 0; r < 2; ++r) {
        for (int i = 0; i < 3; ++i) {
            const float* W = res_w + ((size_t)(r * 3 + i) << 16) + (size_t)kg * 64 * 256 + col;
            const float* zp = zs + kg * 64;
            float a0 = 0, a1 = 0, a2 = 0, a3 = 0;
#pragma unroll
            for (int j = 0; j < 64; j += 4) {
                a0 += zp[j]     * W[(j)     * 256];
                a1 += zp[j + 1] * W[(j + 1) * 256];
                a2 += zp[j + 2] * W[(j + 2) * 256];
                a3 += zp[j + 3] * W[(j + 3) * 256];
            }
            part[kg][col] = (a0 + a1) + (a2 + a3);
            __syncthreads();
            if (kg == 0) {
                zs[col] = silu_f(res_b[(r * 3 + i) * 256 + col]
                                 + part[0][col] + part[1][col] + part[2][col] + part[3][col]);
            }
            __syncthreads();
        }
        if (kg == 0) {
            hv = (hv + zs[col]) * 0.70710678118654752f;
            zs[col] = hv;
        }
        __syncthreads();
    }

    // head: u = silu((hv + t_out) @ w_o1 + b_o1)
    if (kg == 0) zs[col] = hv + t_out[b * 256 + col];
    __syncthreads();
    {
        const float* W = w_o1 + (size_t)kg * 64 * 256 + col;
        const float* zp = zs + kg * 64;
        float a0 = 0, a1 = 0, a2 = 0, a3 = 0;
#pragma unroll
        for (int j = 0; j < 64; j += 4) {
            a0 += zp[j]     * W[(j)     * 256];
            a1 += zp[j + 1] * W[(j + 1) * 256];
            a2 += zp[j + 2] * W[(j + 2) * 256];
            a3 += zp[j + 3] * W[(j + 3) * 256];
        }
        part[kg][col] = (a0 + a1) + (a2 + a3);
    }
    __syncthreads();
    if (kg == 0) {
        u_b[b * 256 + col] = (__bf16)silu_f(b_o1[col]
            + part[0][col] + part[1][col] + part[2][col] + part[3][col]);
    }
}

// Node 9: out[b,n] = sum_h u[b,h] * w_o2[h,n] + b_o2[n]   (K=256, full-K per wave)
__global__ __launch_bounds__(256) void out_gemm_kernel(
    const __bf16* __restrict__ u_b, const __bf16* __restrict__ w_o2T,
    const float* __restrict__ b_o2, float* __restrict__ out)
{
    const int tid = threadIdx.x;
    const int wave = tid >> 6, lane = tid & 63;
    const int l15 = lane & 15, q = lane >> 4;
    const int g = blockIdx.x * 4 + wave;
    const int btile = g & 1;
    const int n0 = (g >> 1) * 32;

    const __bf16* ap  = u_b + (size_t)(btile * 16 + l15) * 256;
    const __bf16* bp0 = w_o2T + (size_t)(n0 + l15) * 256;
    const __bf16* bp1 = w_o2T + (size_t)(n0 + 16 + l15) * 256;

    f32x4 acc0 = {0,0,0,0}, acc1 = {0,0,0,0};
#pragma unroll
    for (int ks = 0; ks < 8; ++ks) {
        const int k = ks * 32 + q * 8;
        bf16x8 a  = *(const bf16x8*)(ap + k);
        bf16x8 b0 = *(const bf16x8*)(bp0 + k);
        bf16x8 b1 = *(const bf16x8*)(bp1 + k);
        acc0 = mfma16(a, b0, acc0);
        acc1 = mfma16(a, b1, acc1);
    }
    const int row = btile * 16 + q * 4;
    const int na = n0 + l15, nb = n0 + 16 + l15;
#pragma unroll
    for (int r = 0; r < 4; ++r) {
        out[(size_t)(row + r) * 4096 + na] = acc0[r] + b_o2[na];
        out[(size_t)(row + r) * 4096 + nb] = acc1[r] + b_o2[nb];
    }
}

extern "C" void kernel_launch(void* const* d_in, const int* in_sizes, int n_in,
                              void* d_out, int out_size, void* d_ws, size_t ws_size,
                              hipStream_t stream)
{
    (void)in_sizes; (void)n_in; (void)out_size; (void)ws_size;
    const float* x     = (const float*)d_in[0];
    const float* t     = (const float*)d_in[1];
    const float* L     = (const float*)d_in[2];
    const float* w_g1  = (const float*)d_in[3];
    const float* w_g2  = (const float*)d_in[4];
    const float* w_t1  = (const float*)d_in[5];
    const float* b_t1  = (const float*)d_in[6];
    const float* w_t2  = (const float*)d_in[7];
    const float* b_t2  = (const float*)d_in[8];
    const float* w_map = (const float*)d_in[9];
    const float* b_map = (const float*)d_in[10];
    const float* res_w = (const float*)d_in[11];
    const float* res_b = (const float*)d_in[12];
    const float* w_o1  = (const float*)d_in[13];
    const float* b_o1  = (const float*)d_in[14];
    const float* w_o2  = (const float*)d_in[15];
    const float* b_o2  = (const float*)d_in[16];
    float* out = (float*)d_out;
    char* ws = (char*)d_ws;

    float* a_c  = (float*)(ws + WS_A);
    float* tout = (float*)(ws + WS_TOUT);
    float* z1   = (float*)(ws + WS_Z1);
    float* z2   = (float*)(ws + WS_Z1 + WS_ZSTR);
    float* z3   = (float*)(ws + WS_Z1 + 2 * WS_ZSTR);
    float* z4   = (float*)(ws + WS_Z1 + 3 * WS_ZSTR);
    float* h0   = (float*)(ws + WS_H0);
    float* g2   = (float*)(ws + WS_G2F);
    __bf16* u_b    = (__bf16*)(ws + WS_UB);
    __bf16* w_mapT = (__bf16*)(ws + WS_WMAPT);
    __bf16* w_o2T  = (__bf16*)(ws + WS_WO2T);

    prep_kernel<<<2601, 256, 0, stream>>>(t, w_g1, w_g2, w_t1, b_t1, w_t2, b_t2,
                                          w_map, w_o2, ws);
    hop_kernel<<<512, 512, 0, stream>>>(L, x,  z1);
    hop_kernel<<<512, 512, 0, stream>>>(L, z1, z2);
    hop_kernel<<<512, 512, 0, stream>>>(L, z2, z3);
    hop_kernel<<<512, 512, 0, stream>>>(L, z3, z4);
    combine_kernel<<<128, 256, 0, stream>>>(x, z1, z2, z3, z4, a_c, g2);
    map_gemm_kernel<<<128, 256, 0, stream>>>(g2, w_mapT, h0);
    resnet_kernel<<<32, 1024, 0, stream>>>(h0, b_map, res_w, res_b, tout, w_o1, b_o1, u_b);
    out_gemm_kernel<<<64, 256, 0, stream>>>(u_b, w_o2T, b_o2, out);
}